// Round 1
// baseline (154.762 us; speedup 1.0000x reference)
//
#include <hip/hip_runtime.h>
#include <hip/hip_bf16.h>

// CapsuleLayer routing, bf16 MFMA, 6 dispatches (r12 structure + micro-opts).
// B=512,P=1152,N=10,T=16,D=8, 3 iters. Verified 16x16x32 bf16 layouts:
//   A: m=lane&15, k=q*8+j   B: n=lane&15, k=q*8+j   D: col=lane&15, row=q*4+r
// r14 changes vs r13:
//  - k_sv: 1024 threads (16 waves x 18 kc, dual-acc 9 iters). Same grid, same
//    total work, 2x waves/SIMD (4->8 on critical-path CUs): the loads are
//    L3-served (written by prior kernel on other XCDs), ~800cy latency needs
//    more TLP than 8 waves/block gave.
//  - k_ga: bred padded [64][40]->[64][41]. Stride 40 dwords == 8 mod 32 was a
//    16-way bank conflict on 120 stores + 120 reads per block; 41 is 2-way.
// Chain prep -> sv0 -> ga0 -> sv1 -> ga1 -> sv2 is structurally minimal:
// r11 proved grid-wide sync costs 4x (agent fences nuke non-coherent XCD L2s).

typedef __attribute__((ext_vector_type(8))) short bfrag;   // 8 bf16
typedef __attribute__((ext_vector_type(4))) float f32x4;

constexpr int B_ = 512, P_ = 1152, N_ = 10, NT_ = 160;
constexpr int K1_ = 9216, NKC_ = 288;

__device__ __forceinline__ unsigned short f2bf(float f) {
    unsigned u = __float_as_uint(f);
    return (unsigned short)((u + 0x7fffu + ((u >> 16) & 1u)) >> 16);  // RNE
}
__device__ __forceinline__ float bf2f(unsigned short s) {
    return __uint_as_float((unsigned)s << 16);
}
__device__ __forceinline__ bfrag mkfrag(f32x4 a, f32x4 b, float c) {
    bfrag f;
    f[0] = (short)f2bf(a.x * c); f[1] = (short)f2bf(a.y * c);
    f[2] = (short)f2bf(a.z * c); f[3] = (short)f2bf(a.w * c);
    f[4] = (short)f2bf(b.x * c); f[5] = (short)f2bf(b.y * c);
    f[6] = (short)f2bf(b.z * c); f[7] = (short)f2bf(b.w * c);
    return f;
}

// Xb:  [mblk 32][kc 288][lane 64][8]  elem = x[mblk*16+col][kc*32+q*8+j]
// Xga: [pdblk 576][kc 16][lane 64][8] elem = x[kc*32+q*8+j][pdblk*16+col]
// Wc:  [n 10][kc 288][lane 64][8]     elem = c[p,n]*W[p][n*16+col][j], p=kc*4+q
// Wb:  [pdblk 576][lane 64][40]       elem(mt*4+r) = W[p][mt*16+q*4+r][d]
__global__ __launch_bounds__(256) void k_prep(const float* __restrict__ x,
                                              const float* __restrict__ W,
                                              unsigned short* __restrict__ Xb,
                                              unsigned short* __restrict__ Xga,
                                              unsigned short* __restrict__ Wc,
                                              unsigned short* __restrict__ Wb) {
    const int bid = blockIdx.x, tid = threadIdx.x;
    const int w = tid >> 6, ln = tid & 63, col = ln & 15, q = ln >> 4;
    if (bid < 1152) {          // x transpose tile -> Xga AND Xb fragments
        __shared__ unsigned short tile[64][72];   // [pd_local][b_local]
        const int pd0 = (bid >> 3) * 64, b0 = (bid & 7) * 64;
        const int c0 = tid & 63, r0 = tid >> 6;
#pragma unroll
        for (int i = 0; i < 16; ++i) {
            const int br = i * 4 + r0;   // coalesced: 64 lanes x 4B contiguous
            tile[c0][br] = f2bf(x[(size_t)(b0 + br) * K1_ + pd0 + c0]);
        }
        __syncthreads();
        // Xga: 8 frags (pdblk_l 0..3, kc_l 0..1); wave w does f=w, f=w+4
#pragma unroll
        for (int fi = 0; fi < 2; ++fi) {
            const int f = w + fi * 4;
            const int pdblk_l = f & 3, kc_l = f >> 2;
            bfrag fr;
#pragma unroll
            for (int j = 0; j < 8; ++j)
                fr[j] = (short)tile[pdblk_l * 16 + col][kc_l * 32 + q * 8 + j];
            const size_t addr = ((size_t)(((pd0 >> 4) + pdblk_l) * 16 + (b0 >> 5) + kc_l)) * 512 + ln * 8;
            *(bfrag*)(Xga + addr) = fr;   // 1KB/wave contiguous
        }
        // Xb: 8 frags (mblk_l 0..3, kc_l 0..1); wave w does f=w, f=w+4
#pragma unroll
        for (int fi = 0; fi < 2; ++fi) {
            const int f = w + fi * 4;
            const int mblk_l = f & 3, kc_l = f >> 2;
            bfrag fr;
#pragma unroll
            for (int j = 0; j < 8; ++j)
                fr[j] = (short)tile[kc_l * 32 + q * 8 + j][mblk_l * 16 + col];
            const size_t addr = ((size_t)(((b0 >> 4) + mblk_l) * NKC_ + (pd0 >> 5) + kc_l)) * 512 + ln * 8;
            *(bfrag*)(Xb + addr) = fr;    // 1KB/wave contiguous
        }
    } else if (bid < 1872) {   // Wc0 = bf16(0.1*W): one wave per (n,kc)
        const int task = (bid - 1152) * 4 + w;     // < 2880 = 10*288
        const int n = task / NKC_, kc = task % NKC_;
        const int p = kc * 4 + q;
        const float* wr = W + ((size_t)p * NT_ + n * 16 + col) * 8;
        const bfrag f = mkfrag(*(const f32x4*)wr, *(const f32x4*)(wr + 4), 0.1f);
        *(bfrag*)(Wc + ((size_t)(n * NKC_ + kc)) * 512 + ln * 8) = f;  // 1KB/wave
    } else {                   // Wb: contraction-layout bf16 W
        const int idx = (bid - 1872) * 256 + tid;   // < 36864
        const int p = ((idx >> 6) * 16 + (idx & 15)) >> 3, d = idx & 7;
        const int q2 = (idx & 63) >> 4;
        unsigned short* dst = Wb + (size_t)idx * 40;
#pragma unroll
        for (int mt = 0; mt < N_; ++mt)
#pragma unroll
            for (int r = 0; r < 4; ++r)
                dst[mt * 4 + r] = f2bf(W[((size_t)p * NT_ + mt * 16 + q2 * 4 + r) * 8 + d]);
    }
}

// ---- GEMM1 + squash. grid (32,10), 1024 thr = 16 waves, 18 K-chunks/wave ----
// Dual accumulators: even/odd kc streams halve the MFMA dependency chain.
__global__ __launch_bounds__(1024) void k_sv(const unsigned short* __restrict__ Xb,
                                             const unsigned short* __restrict__ Wc,
                                             unsigned short* __restrict__ Vt,
                                             float* __restrict__ outp,
                                             int final_it) {
    __shared__ float red[15 * 256];
    const int tid = threadIdx.x;
    const int w = tid >> 6, lane = tid & 63, col = lane & 15, q = lane >> 4;
    const int mblk = blockIdx.x;        // 16 b-rows
    const int n0 = blockIdx.y;          // one n per block

    f32x4 accA = (f32x4){0.f, 0.f, 0.f, 0.f};
    f32x4 accB = (f32x4){0.f, 0.f, 0.f, 0.f};
    const int kc0 = w * 18;             // 18 chunks per wave, processed 2/iter
    const unsigned short* Xp = Xb + ((size_t)(mblk * NKC_ + kc0)) * 512 + lane * 8;
    const unsigned short* W0 = Wc + ((size_t)(n0 * NKC_ + kc0)) * 512 + lane * 8;
#pragma unroll 3
    for (int i = 0; i < 9; ++i) {
        const bfrag a0 = *(const bfrag*)Xp;
        const bfrag b0 = *(const bfrag*)W0;
        const bfrag a1 = *(const bfrag*)(Xp + 512);
        const bfrag b1 = *(const bfrag*)(W0 + 512);
        accA = __builtin_amdgcn_mfma_f32_16x16x32_bf16(a0, b0, accA, 0, 0, 0);
        accB = __builtin_amdgcn_mfma_f32_16x16x32_bf16(a1, b1, accB, 0, 0, 0);
        Xp += 1024; W0 += 1024;
    }
    f32x4 acc;
#pragma unroll
    for (int r = 0; r < 4; ++r) acc[r] = accA[r] + accB[r];
    if (w) {
#pragma unroll
        for (int r = 0; r < 4; ++r)
            red[(w - 1) * 256 + r * 64 + q * 16 + col] = acc[r];
    }
    __syncthreads();
    if (w == 0) {
#pragma unroll
        for (int r = 0; r < 4; ++r) {
            const int li = r * 64 + q * 16 + col;
            float s = acc[r];
#pragma unroll
            for (int j = 0; j < 15; ++j) s += red[j * 256 + li];
            float sq = s * s;                      // t = col (16 lanes)
            sq += __shfl_xor(sq, 1);
            sq += __shfl_xor(sq, 2);
            sq += __shfl_xor(sq, 4);
            sq += __shfl_xor(sq, 8);
            const float norm = sqrtf(sq);
            const float scale = sq / (1.0f + sq * (norm + 1e-9f));
            const float vv = s * scale;
            const int b = mblk * 16 + q * 4 + r;
            const int nt = n0 * 16 + col;
            if (final_it) outp[(size_t)b * NT_ + nt] = vv;
            else          Vt[(size_t)nt * B_ + b] = f2bf(vv);
        }
    }
}

// ---- GEMM2 + contraction + softmax + Wc rebuild. grid 576, 256 thr --------
__global__ __launch_bounds__(256) void k_ga(const unsigned short* __restrict__ Vt,
                                            const unsigned short* __restrict__ Xga,
                                            const unsigned short* __restrict__ Wb,
                                            const float* __restrict__ W,
                                            float* __restrict__ bbar,
                                            unsigned short* __restrict__ Wc,
                                            int accum) {
    __shared__ float bred[3][64][41];   // 41: stride 40 was 16-way bank conflict
    __shared__ float csm[2][N_];
    const int tid = threadIdx.x;
    const int w = tid >> 6, lane = tid & 63, col = lane & 15, q = lane >> 4;
    const int pdblk = blockIdx.x;
    const int p = (pdblk * 16 + col) >> 3, d = col & 7;

    f32x4 acc[N_];
#pragma unroll
    for (int mt = 0; mt < N_; ++mt) acc[mt] = (f32x4){0.f, 0.f, 0.f, 0.f};

    const int kb0 = w * 4;
#pragma unroll
    for (int kc = kb0; kc < kb0 + 4; ++kc) {
        const bfrag bf = *(const bfrag*)(Xga + ((size_t)(pdblk * 16 + kc)) * 512 + lane * 8);
#pragma unroll
        for (int mt = 0; mt < N_; ++mt) {
            const bfrag af = *(const bfrag*)(Vt + (size_t)(mt * 16 + col) * B_ + kc * 32 + q * 8);
            acc[mt] = __builtin_amdgcn_mfma_f32_16x16x32_bf16(af, bf, acc[mt], 0, 0, 0);
        }
    }
    if (w) {
#pragma unroll
        for (int mt = 0; mt < N_; ++mt)
#pragma unroll
            for (int r = 0; r < 4; ++r)
                bred[w - 1][lane][mt * 4 + r] = acc[mt][r];
    }
    __syncthreads();
    if (w == 0) {
        unsigned short wv[40];
        const unsigned short* ws2 = Wb + ((size_t)(pdblk * 64 + lane)) * 40;
#pragma unroll
        for (int v = 0; v < 40; ++v) wv[v] = ws2[v];
        float part[N_];
#pragma unroll
        for (int mt = 0; mt < N_; ++mt) {
            float s = 0.f;
#pragma unroll
            for (int r = 0; r < 4; ++r) {
                const float h = acc[mt][r] + bred[0][lane][mt * 4 + r]
                              + bred[1][lane][mt * 4 + r] + bred[2][lane][mt * 4 + r];
                s = fmaf(bf2f(wv[mt * 4 + r]), h, s);
            }
            s += __shfl_xor(s, 1);    // reduce over d
            s += __shfl_xor(s, 2);
            s += __shfl_xor(s, 4);
            s += __shfl_xor(s, 16);   // reduce over t-quarters
            s += __shfl_xor(s, 32);
            part[mt] = s;
        }
        if (q == 0 && d == 0) {       // lanes 0 and 8: the block's 2 p's
            const int pl = col >> 3;
            float bv[N_];
#pragma unroll
            for (int mt = 0; mt < N_; ++mt) {
                bv[mt] = part[mt] * (1.0f / 512.0f);
                if (accum) bv[mt] += bbar[(size_t)p * N_ + mt];
                bbar[(size_t)p * N_ + mt] = bv[mt];
            }
            float m = -1e30f;
#pragma unroll
            for (int mt = 0; mt < N_; ++mt) m = fmaxf(m, bv[mt]);
            float sum = 0.f;
#pragma unroll
            for (int mt = 0; mt < N_; ++mt) { bv[mt] = __expf(bv[mt] - m); sum += bv[mt]; }
            const float inv = 1.f / sum;
#pragma unroll
            for (int mt = 0; mt < N_; ++mt) csm[pl][mt] = bv[mt] * inv;
        }
    }
    __syncthreads();
    const int p0 = pdblk * 2;
#pragma unroll
    for (int task = tid; task < 320; task += 256) {   // Wc rebuild (2 p's)
        const int pl = task / 160, rem = task % 160;
        const int n = rem >> 4, cl = rem & 15;
        const int pp = p0 + pl;
        const float c = csm[pl][n];
        const float* wr = W + ((size_t)pp * NT_ + n * 16 + cl) * 8;
        const size_t addr = ((size_t)(n * NKC_ + (pp >> 2))) * 512 + (pp & 3) * 128 + cl * 8;
        *(bfrag*)(Wc + addr) = mkfrag(*(const f32x4*)wr, *(const f32x4*)(wr + 4), c);
    }
}

extern "C" void kernel_launch(void* const* d_in, const int* in_sizes, int n_in,
                              void* d_out, int out_size, void* d_ws, size_t ws_size,
                              hipStream_t stream) {
    const float* x = (const float*)d_in[0];   // fp32 [B][P*D]
    const float* W = (const float*)d_in[1];   // fp32 [P][NT][D]

    char* wsp = (char*)d_ws;
    float* bbar = (float*)wsp;                                      // 46080 B
    unsigned short* Xb  = (unsigned short*)(wsp + 46080);           // 9.44 MB
    unsigned short* Xga = Xb + (size_t)32 * NKC_ * 512;             // 9.44 MB
    unsigned short* Wc  = Xga + (size_t)576 * 16 * 512;             // 2.95 MB
    unsigned short* Wb  = Wc + (size_t)N_ * NKC_ * 512;             // 2.95 MB
    unsigned short* Vt  = Wb + (size_t)576 * 64 * 40;               // 160 KB
    float* outp = (float*)d_out;

    k_prep<<<dim3(2016), dim3(256), 0, stream>>>(x, W, Xb, Xga, Wc, Wb);
    k_sv<<<dim3(32, 10), dim3(1024), 0, stream>>>(Xb, Wc, Vt, outp, 0);
    k_ga<<<dim3(576), dim3(256), 0, stream>>>(Vt, Xga, Wb, W, bbar, Wc, 0);
    k_sv<<<dim3(32, 10), dim3(1024), 0, stream>>>(Xb, Wc, Vt, outp, 0);
    k_ga<<<dim3(576), dim3(256), 0, stream>>>(Vt, Xga, Wb, W, bbar, Wc, 1);
    k_sv<<<dim3(32, 10), dim3(1024), 0, stream>>>(Xb, Wc, Vt, outp, 1);
}

// Round 2
// 136.139 us; speedup vs baseline: 1.1368x; 1.1368x over previous
//
#include <hip/hip_runtime.h>
#include <hip/hip_bf16.h>

// CapsuleLayer routing, bf16 MFMA, 6 dispatches.
// B=512,P=1152,N=10,T=16,D=8, 3 iters. Verified 16x16x32 bf16 layouts:
//   A: m=lane&15, k=q*8+j   B: n=lane&15, k=q*8+j   D: col=lane&15, row=q*4+r
// r15 changes vs r14 (r14: TLP x2 + LDS pad both NEUTRAL -> not latency/LDS
// bound; attack L2 TRAFFIC instead):
//  - k_sv: 2 n's per block, grid (32,5)x1024thr. Xb frag loaded once feeds
//    both n-MFMAs (accA/accB keep the dual-chain). L2 traffic 189->142MB,
//    160 blocks = 1/CU (no 2-block straggler CUs).
//  - Vt stored in MFMA-fragment layout [kc16][mt10][lane][8]: k_ga A-loads
//    are 1KB contiguous per wave (was 16 scattered 64B sectors each).
//  - k_ga: 2 pdblk per block (grid 288, 512thr); both halves read the same
//    Vt frags -> L1 reuse halves Vt L2 traffic (92->~46MB/dispatch).
// Chain prep -> sv0 -> ga0 -> sv1 -> ga1 -> sv2 is structurally minimal:
// r11 proved grid-wide sync costs 4x (agent fences nuke non-coherent XCD L2s).

typedef __attribute__((ext_vector_type(8))) short bfrag;   // 8 bf16
typedef __attribute__((ext_vector_type(4))) float f32x4;

constexpr int B_ = 512, P_ = 1152, N_ = 10, NT_ = 160;
constexpr int K1_ = 9216, NKC_ = 288;

__device__ __forceinline__ unsigned short f2bf(float f) {
    unsigned u = __float_as_uint(f);
    return (unsigned short)((u + 0x7fffu + ((u >> 16) & 1u)) >> 16);  // RNE
}
__device__ __forceinline__ float bf2f(unsigned short s) {
    return __uint_as_float((unsigned)s << 16);
}
__device__ __forceinline__ bfrag mkfrag(f32x4 a, f32x4 b, float c) {
    bfrag f;
    f[0] = (short)f2bf(a.x * c); f[1] = (short)f2bf(a.y * c);
    f[2] = (short)f2bf(a.z * c); f[3] = (short)f2bf(a.w * c);
    f[4] = (short)f2bf(b.x * c); f[5] = (short)f2bf(b.y * c);
    f[6] = (short)f2bf(b.z * c); f[7] = (short)f2bf(b.w * c);
    return f;
}

// Xb:  [mblk 32][kc 288][lane 64][8]  elem = x[mblk*16+col][kc*32+q*8+j]
// Xga: [pdblk 576][kc 16][lane 64][8] elem = x[kc*32+q*8+j][pdblk*16+col]
// Wc:  [n 10][kc 288][lane 64][8]     elem = c[p,n]*W[p][n*16+col][j], p=kc*4+q
// Wb:  [pdblk 576][lane 64][40]       elem(mt*4+r) = W[p][mt*16+q*4+r][d]
// Vt:  [kc 16][mt 10][lane 64][8]     elem = v[kc*32+q*8+j][mt*16+col]  (bf16)
__global__ __launch_bounds__(256) void k_prep(const float* __restrict__ x,
                                              const float* __restrict__ W,
                                              unsigned short* __restrict__ Xb,
                                              unsigned short* __restrict__ Xga,
                                              unsigned short* __restrict__ Wc,
                                              unsigned short* __restrict__ Wb) {
    const int bid = blockIdx.x, tid = threadIdx.x;
    const int w = tid >> 6, ln = tid & 63, col = ln & 15, q = ln >> 4;
    if (bid < 1152) {          // x transpose tile -> Xga AND Xb fragments
        __shared__ unsigned short tile[64][72];   // [pd_local][b_local]
        const int pd0 = (bid >> 3) * 64, b0 = (bid & 7) * 64;
        const int c0 = tid & 63, r0 = tid >> 6;
#pragma unroll
        for (int i = 0; i < 16; ++i) {
            const int br = i * 4 + r0;   // coalesced: 64 lanes x 4B contiguous
            tile[c0][br] = f2bf(x[(size_t)(b0 + br) * K1_ + pd0 + c0]);
        }
        __syncthreads();
        // Xga: 8 frags (pdblk_l 0..3, kc_l 0..1); wave w does f=w, f=w+4
#pragma unroll
        for (int fi = 0; fi < 2; ++fi) {
            const int f = w + fi * 4;
            const int pdblk_l = f & 3, kc_l = f >> 2;
            bfrag fr;
#pragma unroll
            for (int j = 0; j < 8; ++j)
                fr[j] = (short)tile[pdblk_l * 16 + col][kc_l * 32 + q * 8 + j];
            const size_t addr = ((size_t)(((pd0 >> 4) + pdblk_l) * 16 + (b0 >> 5) + kc_l)) * 512 + ln * 8;
            *(bfrag*)(Xga + addr) = fr;   // 1KB/wave contiguous
        }
        // Xb: 8 frags (mblk_l 0..3, kc_l 0..1); wave w does f=w, f=w+4
#pragma unroll
        for (int fi = 0; fi < 2; ++fi) {
            const int f = w + fi * 4;
            const int mblk_l = f & 3, kc_l = f >> 2;
            bfrag fr;
#pragma unroll
            for (int j = 0; j < 8; ++j)
                fr[j] = (short)tile[kc_l * 32 + q * 8 + j][mblk_l * 16 + col];
            const size_t addr = ((size_t)(((b0 >> 4) + mblk_l) * NKC_ + (pd0 >> 5) + kc_l)) * 512 + ln * 8;
            *(bfrag*)(Xb + addr) = fr;    // 1KB/wave contiguous
        }
    } else if (bid < 1872) {   // Wc0 = bf16(0.1*W): one wave per (n,kc)
        const int task = (bid - 1152) * 4 + w;     // < 2880 = 10*288
        const int n = task / NKC_, kc = task % NKC_;
        const int p = kc * 4 + q;
        const float* wr = W + ((size_t)p * NT_ + n * 16 + col) * 8;
        const bfrag f = mkfrag(*(const f32x4*)wr, *(const f32x4*)(wr + 4), 0.1f);
        *(bfrag*)(Wc + ((size_t)(n * NKC_ + kc)) * 512 + ln * 8) = f;  // 1KB/wave
    } else {                   // Wb: contraction-layout bf16 W
        const int idx = (bid - 1872) * 256 + tid;   // < 36864
        const int p = ((idx >> 6) * 16 + (idx & 15)) >> 3, d = idx & 7;
        const int q2 = (idx & 63) >> 4;
        unsigned short* dst = Wb + (size_t)idx * 40;
#pragma unroll
        for (int mt = 0; mt < N_; ++mt)
#pragma unroll
            for (int r = 0; r < 4; ++r)
                dst[mt * 4 + r] = f2bf(W[((size_t)p * NT_ + mt * 16 + q2 * 4 + r) * 8 + d]);
    }
}

// ---- GEMM1 + squash. grid (32,5), 1024 thr = 16 waves, 2 n's per block ----
// Each Xb frag feeds two MFMAs (n0, n0+1): -25% L2 traffic + dual acc chain.
__global__ __launch_bounds__(1024) void k_sv(const unsigned short* __restrict__ Xb,
                                             const unsigned short* __restrict__ Wc,
                                             unsigned short* __restrict__ Vt,
                                             float* __restrict__ outp,
                                             int final_it) {
    __shared__ float red[16][2][256];   // 32KB: all 16 waves x {n0,n1}
    const int tid = threadIdx.x;
    const int w = tid >> 6, lane = tid & 63, col = lane & 15, q = lane >> 4;
    const int mblk = blockIdx.x;        // 16 b-rows
    const int n0 = blockIdx.y * 2;      // two n per block

    f32x4 accA = (f32x4){0.f, 0.f, 0.f, 0.f};
    f32x4 accB = (f32x4){0.f, 0.f, 0.f, 0.f};
    const int kc0 = w * 18;             // 18 chunks per wave
    const unsigned short* Xp = Xb + ((size_t)(mblk * NKC_ + kc0)) * 512 + lane * 8;
    const unsigned short* W0 = Wc + ((size_t)(n0 * NKC_ + kc0)) * 512 + lane * 8;
    const unsigned short* W1 = W0 + (size_t)NKC_ * 512;
#pragma unroll 3
    for (int i = 0; i < 18; ++i) {
        const bfrag a  = *(const bfrag*)Xp;
        const bfrag b0 = *(const bfrag*)W0;
        const bfrag b1 = *(const bfrag*)W1;
        accA = __builtin_amdgcn_mfma_f32_16x16x32_bf16(a, b0, accA, 0, 0, 0);
        accB = __builtin_amdgcn_mfma_f32_16x16x32_bf16(a, b1, accB, 0, 0, 0);
        Xp += 512; W0 += 512; W1 += 512;
    }
#pragma unroll
    for (int r = 0; r < 4; ++r) {
        red[w][0][r * 64 + q * 16 + col] = accA[r];
        red[w][1][r * 64 + q * 16 + col] = accB[r];
    }
    __syncthreads();
    if (w < 2) {                        // wave 0 -> n0, wave 1 -> n0+1
        const int mt = n0 + w;
#pragma unroll
        for (int r = 0; r < 4; ++r) {
            const int li = r * 64 + q * 16 + col;
            float s = 0.f;
#pragma unroll
            for (int j = 0; j < 16; ++j) s += red[j][w][li];
            float sq = s * s;                      // t = col (16 lanes)
            sq += __shfl_xor(sq, 1);
            sq += __shfl_xor(sq, 2);
            sq += __shfl_xor(sq, 4);
            sq += __shfl_xor(sq, 8);
            const float norm = sqrtf(sq);
            const float scale = sq / (1.0f + sq * (norm + 1e-9f));
            const float vv = s * scale;
            const int b = mblk * 16 + q * 4 + r;
            if (final_it) {
                outp[(size_t)b * NT_ + mt * 16 + col] = vv;
            } else {
                const int b5 = b & 31;             // fragment layout write
                Vt[((size_t)((mblk >> 1) * N_ + mt)) * 512
                   + ((b5 >> 3) * 16 + col) * 8 + (b5 & 7)] = f2bf(vv);
            }
        }
    }
}

// ---- GEMM2 + contraction + softmax + Wc rebuild. grid 288, 512 thr -------
// Two pdblk per block (halves share Vt frags -> L1 reuse halves Vt traffic).
__global__ __launch_bounds__(512) void k_ga(const unsigned short* __restrict__ Vt,
                                            const unsigned short* __restrict__ Xga,
                                            const unsigned short* __restrict__ Wb,
                                            const float* __restrict__ W,
                                            float* __restrict__ bbar,
                                            unsigned short* __restrict__ Wc,
                                            int accum) {
    __shared__ float bred[2][3][64][41];   // per half: 3 storing waves
    __shared__ float csm[4][N_];
    const int tid = threadIdx.x;
    const int w = tid >> 6, lane = tid & 63, col = lane & 15, q = lane >> 4;
    const int half = w >> 2, wl = w & 3;
    const int pdblk = blockIdx.x * 2 + half;
    const int p = (pdblk * 16 + col) >> 3, d = col & 7;

    f32x4 acc[N_];
#pragma unroll
    for (int mt = 0; mt < N_; ++mt) acc[mt] = (f32x4){0.f, 0.f, 0.f, 0.f};

    const int kb0 = wl * 4;
#pragma unroll
    for (int kc = kb0; kc < kb0 + 4; ++kc) {
        const bfrag bf = *(const bfrag*)(Xga + ((size_t)(pdblk * 16 + kc)) * 512 + lane * 8);
#pragma unroll
        for (int mt = 0; mt < N_; ++mt) {
            const bfrag af = *(const bfrag*)(Vt + ((size_t)(kc * N_ + mt)) * 512 + lane * 8);
            acc[mt] = __builtin_amdgcn_mfma_f32_16x16x32_bf16(af, bf, acc[mt], 0, 0, 0);
        }
    }
    if (wl) {
#pragma unroll
        for (int mt = 0; mt < N_; ++mt)
#pragma unroll
            for (int r = 0; r < 4; ++r)
                bred[half][wl - 1][lane][mt * 4 + r] = acc[mt][r];
    }
    __syncthreads();
    if (wl == 0) {
        unsigned short wv[40];
        const unsigned short* ws2 = Wb + ((size_t)(pdblk * 64 + lane)) * 40;
#pragma unroll
        for (int v = 0; v < 40; ++v) wv[v] = ws2[v];
        float part[N_];
#pragma unroll
        for (int mt = 0; mt < N_; ++mt) {
            float s = 0.f;
#pragma unroll
            for (int r = 0; r < 4; ++r) {
                const float h = acc[mt][r] + bred[half][0][lane][mt * 4 + r]
                              + bred[half][1][lane][mt * 4 + r]
                              + bred[half][2][lane][mt * 4 + r];
                s = fmaf(bf2f(wv[mt * 4 + r]), h, s);
            }
            s += __shfl_xor(s, 1);    // reduce over d
            s += __shfl_xor(s, 2);
            s += __shfl_xor(s, 4);
            s += __shfl_xor(s, 16);   // reduce over t-quarters
            s += __shfl_xor(s, 32);
            part[mt] = s;
        }
        if (q == 0 && d == 0) {       // lanes 0 and 8: this half's 2 p's
            const int pl = col >> 3;
            float bv[N_];
#pragma unroll
            for (int mt = 0; mt < N_; ++mt) {
                bv[mt] = part[mt] * (1.0f / 512.0f);
                if (accum) bv[mt] += bbar[(size_t)p * N_ + mt];
                bbar[(size_t)p * N_ + mt] = bv[mt];
            }
            float m = -1e30f;
#pragma unroll
            for (int mt = 0; mt < N_; ++mt) m = fmaxf(m, bv[mt]);
            float sum = 0.f;
#pragma unroll
            for (int mt = 0; mt < N_; ++mt) { bv[mt] = __expf(bv[mt] - m); sum += bv[mt]; }
            const float inv = 1.f / sum;
#pragma unroll
            for (int mt = 0; mt < N_; ++mt) csm[half * 2 + pl][mt] = bv[mt] * inv;
        }
    }
    __syncthreads();
    const int p0 = blockIdx.x * 4;
#pragma unroll
    for (int task = tid; task < 640; task += 512) {   // Wc rebuild (4 p's)
        const int pl = task / 160, rem = task % 160;
        const int n = rem >> 4, cl = rem & 15;
        const int pp = p0 + pl;
        const float c = csm[pl][n];
        const float* wr = W + ((size_t)pp * NT_ + n * 16 + cl) * 8;
        const size_t addr = ((size_t)(n * NKC_ + (pp >> 2))) * 512 + (pp & 3) * 128 + cl * 8;
        *(bfrag*)(Wc + addr) = mkfrag(*(const f32x4*)wr, *(const f32x4*)(wr + 4), c);
    }
}

extern "C" void kernel_launch(void* const* d_in, const int* in_sizes, int n_in,
                              void* d_out, int out_size, void* d_ws, size_t ws_size,
                              hipStream_t stream) {
    const float* x = (const float*)d_in[0];   // fp32 [B][P*D]
    const float* W = (const float*)d_in[1];   // fp32 [P][NT][D]

    char* wsp = (char*)d_ws;
    float* bbar = (float*)wsp;                                      // 46080 B
    unsigned short* Xb  = (unsigned short*)(wsp + 46080);           // 9.44 MB
    unsigned short* Xga = Xb + (size_t)32 * NKC_ * 512;             // 9.44 MB
    unsigned short* Wc  = Xga + (size_t)576 * 16 * 512;             // 2.95 MB
    unsigned short* Wb  = Wc + (size_t)N_ * NKC_ * 512;             // 2.95 MB
    unsigned short* Vt  = Wb + (size_t)576 * 64 * 40;               // 160 KB
    float* outp = (float*)d_out;

    k_prep<<<dim3(2016), dim3(256), 0, stream>>>(x, W, Xb, Xga, Wc, Wb);
    k_sv<<<dim3(32, 5), dim3(1024), 0, stream>>>(Xb, Wc, Vt, outp, 0);
    k_ga<<<dim3(288), dim3(512), 0, stream>>>(Vt, Xga, Wb, W, bbar, Wc, 0);
    k_sv<<<dim3(32, 5), dim3(1024), 0, stream>>>(Xb, Wc, Vt, outp, 0);
    k_ga<<<dim3(288), dim3(512), 0, stream>>>(Vt, Xga, Wb, W, bbar, Wc, 1);
    k_sv<<<dim3(32, 5), dim3(1024), 0, stream>>>(Xb, Wc, Vt, outp, 1);
}